// Round 14
// baseline (136.994 us; speedup 1.0000x reference)
//
#include <hip/hip_runtime.h>

#define T_TOKENS 8192
#define D_MODEL  4096
#define N_EXP    64
#define TAU      4e-6f        // gap threshold for f64 repair

typedef __attribute__((ext_vector_type(8))) short bf16x8;   // 8 bf16 (4 VGPR)
typedef __attribute__((ext_vector_type(4))) float f32x4;

#define MFMA(A,B,C) __builtin_amdgcn_mfma_f32_16x16x32_bf16(A, B, C, 0, 0, 0)

__device__ __forceinline__ unsigned short bf16rne(float x) {
    unsigned u = __float_as_uint(x);
    return (unsigned short)((u + 0x7FFFu + ((u >> 16) & 1u)) >> 16);
}
__device__ __forceinline__ unsigned pack2(float a, float b, float& ra, float& rb) {
    unsigned short ha = bf16rne(a), hb = bf16rne(b);
    ra = a - __uint_as_float((unsigned)ha << 16);
    rb = b - __uint_as_float((unsigned)hb << 16);
    return (unsigned)ha | ((unsigned)hb << 16);
}
__device__ __forceinline__ void cvt8(const float4& a, const float4& b,
                                     uint4& hi, uint4& lo) {
    float r0,r1,r2,r3,r4,r5,r6,r7;
    hi.x = pack2(a.x, a.y, r0, r1);
    hi.y = pack2(a.z, a.w, r2, r3);
    hi.z = pack2(b.x, b.y, r4, r5);
    hi.w = pack2(b.z, b.w, r6, r7);
    lo.x = (unsigned)bf16rne(r0) | ((unsigned)bf16rne(r1) << 16);
    lo.y = (unsigned)bf16rne(r2) | ((unsigned)bf16rne(r3) << 16);
    lo.z = (unsigned)bf16rne(r4) | ((unsigned)bf16rne(r5) << 16);
    lo.w = (unsigned)bf16rne(r6) | ((unsigned)bf16rne(r7) << 16);
}

// ---------------------------------------------------------------------------
// Kernel 1: split-bf16 MFMA partial GEMM (hh*wh + hh*wl + hl*wh; err sigma
// ~2.5e-8 << TAU). R13 + DEPTH-2 register prefetch: two named reg sets A/B;
// gload(it+2) issued at tile TOP -> ~2 tiles of coverage before the
// vmcnt-wait at writebuf (was ~0.5 tile: issued at top, awaited same tile).
// Single MFMA body (R7 lesson: duplicated unrolled bodies explode VGPR).
// ---------------------------------------------------------------------------
__global__ __launch_bounds__(256) void k_gemm(const float* __restrict__ h,
                                              const float* __restrict__ w,
                                              float* __restrict__ part,
                                              int ks_len,
                                              int* __restrict__ flag_cnt) {
    __shared__ unsigned short LHS[2][2][128][40]; // [dbuf][hi/lo][tok][kpad] 40 KB
    __shared__ unsigned short LWS[2][2][64][40];  // 20 KB  => 60 KB total
    const int tid  = threadIdx.x;
    const int wv   = tid >> 6;
    const int lane = tid & 63;
    const int T0   = blockIdx.x * 128;
    const int k0   = blockIdx.y * ks_len;
    const int wr   = wv & 1;        // token half (64 tokens)
    const int wc   = wv >> 1;       // expert half (32 experts)
    const int lq   = lane >> 4;     // quarter 0..3
    const int lr   = lane & 15;
    const int koff = lq * 8;        // frag k-offset (bf16 elems)

    if (blockIdx.x == 0 && blockIdx.y == 0 && tid == 0) *flag_cnt = 0;

    const int hrow = tid & 127, hq = (tid >> 7) * 16;
    const int wrow = tid & 63,  wq = (tid >> 6) * 8;
    const float* gh = h + (size_t)(T0 + hrow) * D_MODEL + k0 + hq;
    const float* gw = w + (size_t)wrow * D_MODEL + k0 + wq;

    f32x4 acc[4][2];
#pragma unroll
    for (int i = 0; i < 4; ++i)
#pragma unroll
        for (int j = 0; j < 2; ++j)
#pragma unroll
            for (int x = 0; x < 4; ++x) acc[i][j][x] = 0.f;

    // two static prefetch reg sets (depth-2 pipeline)
    float4 h0A, h1A, h2A, h3A, w0A, w1A;
    float4 h0B, h1B, h2B, h3B, w0B, w1B;
    auto gloadA = [&](int it) {
        const float* p = gh + it * 32;
        h0A = *(const float4*)(p);      h1A = *(const float4*)(p + 4);
        h2A = *(const float4*)(p + 8);  h3A = *(const float4*)(p + 12);
        const float* q = gw + it * 32;
        w0A = *(const float4*)(q);      w1A = *(const float4*)(q + 4);
    };
    auto gloadB = [&](int it) {
        const float* p = gh + it * 32;
        h0B = *(const float4*)(p);      h1B = *(const float4*)(p + 4);
        h2B = *(const float4*)(p + 8);  h3B = *(const float4*)(p + 12);
        const float* q = gw + it * 32;
        w0B = *(const float4*)(q);      w1B = *(const float4*)(q + 4);
    };
    auto writebufA = [&](int nb) {
        uint4 hi, lo;
        cvt8(h0A, h1A, hi, lo);
        *(uint4*)&LHS[nb][0][hrow][hq]     = hi;
        *(uint4*)&LHS[nb][1][hrow][hq]     = lo;
        cvt8(h2A, h3A, hi, lo);
        *(uint4*)&LHS[nb][0][hrow][hq + 8] = hi;
        *(uint4*)&LHS[nb][1][hrow][hq + 8] = lo;
        cvt8(w0A, w1A, hi, lo);
        *(uint4*)&LWS[nb][0][wrow][wq]     = hi;
        *(uint4*)&LWS[nb][1][wrow][wq]     = lo;
    };
    auto writebufB = [&](int nb) {
        uint4 hi, lo;
        cvt8(h0B, h1B, hi, lo);
        *(uint4*)&LHS[nb][0][hrow][hq]     = hi;
        *(uint4*)&LHS[nb][1][hrow][hq]     = lo;
        cvt8(h2B, h3B, hi, lo);
        *(uint4*)&LHS[nb][0][hrow][hq + 8] = hi;
        *(uint4*)&LHS[nb][1][hrow][hq + 8] = lo;
        cvt8(w0B, w1B, hi, lo);
        *(uint4*)&LWS[nb][0][wrow][wq]     = hi;
        *(uint4*)&LWS[nb][1][wrow][wq]     = lo;
    };

    const int nt = ks_len >> 5;         // 16 tiles at KS=8 (even, >=2)
    gloadA(0);                          // tile 0 -> setA
    gloadB(1);                          // tile 1 -> setB (in flight during A-wait)
    writebufA(0);                       // LDS0 (vmcnt waits setA only)
    __syncthreads();
    for (int it = 0; it < nt; ++it) {
        const int b = it & 1;
        // top-of-tile: reload the set consumed LAST tile with tile it+2
        if (it + 2 < nt) { if (b == 0) gloadA(it + 2); else gloadB(it + 2); }
        // MFMA phase (single body, runtime b)
        const bf16x8 Bh0 = *(const bf16x8*)&LWS[b][0][wc * 32 + lr][koff];
        const bf16x8 Bl0 = *(const bf16x8*)&LWS[b][1][wc * 32 + lr][koff];
        const bf16x8 Bh1 = *(const bf16x8*)&LWS[b][0][wc * 32 + 16 + lr][koff];
        const bf16x8 Bl1 = *(const bf16x8*)&LWS[b][1][wc * 32 + 16 + lr][koff];
#pragma unroll
        for (int i4 = 0; i4 < 4; ++i4) {
            const bf16x8 Ah = *(const bf16x8*)&LHS[b][0][wr * 64 + i4 * 16 + lr][koff];
            const bf16x8 Al = *(const bf16x8*)&LHS[b][1][wr * 64 + i4 * 16 + lr][koff];
            acc[i4][0] = MFMA(Ah, Bh0, acc[i4][0]);
            acc[i4][1] = MFMA(Ah, Bh1, acc[i4][1]);
            acc[i4][0] = MFMA(Ah, Bl0, acc[i4][0]);
            acc[i4][1] = MFMA(Ah, Bl1, acc[i4][1]);
            acc[i4][0] = MFMA(Al, Bh0, acc[i4][0]);
            acc[i4][1] = MFMA(Al, Bh1, acc[i4][1]);
        }
        // write tile it+1 into the other LDS buffer (vmcnt-wait: ~2 tiles old)
        if (it + 1 < nt) { if (b == 0) writebufB(b ^ 1); else writebufA(b ^ 1); }
        __syncthreads();
    }

    // C/D layout (m89-verified): col = lane&15, row = (lane>>4)*4 + reg
    float* pb = part + (size_t)blockIdx.y * T_TOKENS * N_EXP;
#pragma unroll
    for (int i4 = 0; i4 < 4; ++i4)
#pragma unroll
        for (int j = 0; j < 2; ++j)
#pragma unroll
            for (int i = 0; i < 4; ++i) {
                const int t = T0 + wr * 64 + i4 * 16 + lq * 4 + i;
                const int e = wc * 32 + j * 16 + lr;
                pb[(size_t)t * N_EXP + e] = acc[i4][j][i];
            }
}

// ---------------------------------------------------------------------------
// Kernel 2: per-token softmax + top-8 + gap-based tie flagging + aux partials.
// block 256 (4 waves), wave handles 4 tokens, lane = expert. f32 throughout.
// ---------------------------------------------------------------------------
__global__ __launch_bounds__(256) void k_router(const float* __restrict__ part, int KS,
                                                float* __restrict__ out_idx,
                                                float* __restrict__ out_w,
                                                float* __restrict__ expsum,
                                                int* __restrict__ flag_cnt,
                                                int* __restrict__ flag_list) {
    __shared__ float laux[4][64];
    const int lane = threadIdx.x & 63;
    const int wid  = threadIdx.x >> 6;
    float aux_acc = 0.f;
    const int tbase = blockIdx.x * 16 + wid * 4;
    const size_t kstride = (size_t)T_TOKENS * N_EXP;

    for (int tt = 0; tt < 4; ++tt) {
        const int t = tbase + tt;
        const float* pb = part + (size_t)t * N_EXP + lane;
        float a0 = 0.f, a1 = 0.f, a2 = 0.f, a3 = 0.f;
        int ksi = 0;
        for (; ksi + 4 <= KS; ksi += 4) {
            a0 += pb[(size_t)(ksi + 0) * kstride];
            a1 += pb[(size_t)(ksi + 1) * kstride];
            a2 += pb[(size_t)(ksi + 2) * kstride];
            a3 += pb[(size_t)(ksi + 3) * kstride];
        }
        for (; ksi < KS; ++ksi) a0 += pb[(size_t)ksi * kstride];
        const float lg = (a0 + a1) + (a2 + a3);

        float m = lg;
#pragma unroll
        for (int off = 32; off; off >>= 1) m = fmaxf(m, __shfl_xor(m, off));
        const float p = __expf(lg - m);
        float s = p;
#pragma unroll
        for (int off = 32; off; off >>= 1) s += __shfl_xor(s, off);
        const float inv_s = 1.f / s;
        aux_acc += p * inv_s;

        float pv = lg; int pi = lane;
        float myp = 0.f; int myi = 0; float tsum = 0.f, prev = 0.f;
        bool flg = false;
#pragma unroll
        for (int r = 0; r < 9; ++r) {
            float bv = pv; int bi = pi;
#pragma unroll
            for (int off = 32; off; off >>= 1) {
                const float ov = __shfl_xor(bv, off);
                const int   oi = __shfl_xor(bi, off);
                if (ov > bv || (ov == bv && oi < bi)) { bv = ov; bi = oi; }
            }
            if (r > 0) flg = flg || (prev - bv < TAU);
            prev = bv;
            if (r < 8) {
                const float bp = __expf(bv - m) * inv_s;
                tsum += bp;
                if (lane == r)  { myp = bp; myi = bi; }
                if (lane == bi) pv = -1e30f;
            }
        }
        if (lane < 8) {
            out_idx[(size_t)t * 8 + lane] = (float)myi;
            out_w[(size_t)t * 8 + lane]   = myp / tsum;
        }
        if (lane == 0 && flg) {
            const int pos = atomicAdd(flag_cnt, 1);
            if (pos < T_TOKENS) flag_list[pos] = t;
        }
    }

    laux[wid][lane] = aux_acc;
    __syncthreads();
    if (threadIdx.x < 64)
        expsum[(size_t)blockIdx.x * 64 + threadIdx.x] =
            laux[0][threadIdx.x] + laux[1][threadIdx.x] +
            laux[2][threadIdx.x] + laux[3][threadIdx.x];
}

// ---------------------------------------------------------------------------
// Kernel 3: f64 repair (one block per flagged token) + FUSED aux finalize.
// ---------------------------------------------------------------------------
__global__ __launch_bounds__(256) void k_repair(const float* __restrict__ h,
                                                const float* __restrict__ w,
                                                const int* __restrict__ flag_cnt,
                                                const int* __restrict__ flag_list,
                                                float* __restrict__ out_idx,
                                                float* __restrict__ out_w,
                                                const float* __restrict__ expsum,
                                                int nb,
                                                float* __restrict__ out_aux) {
    __shared__ float  sh[D_MODEL];   // 16 KB
    __shared__ double sp[4][64];     //  2 KB
    __shared__ float  lx[4][64];     //  1 KB (aux)
    const int tid  = threadIdx.x;
    const int lane = tid & 63;
    const int c    = tid >> 6;

    if (blockIdx.x == 0) {           // fused aux finalize
        float s = 0.f;
        for (int b = c; b < nb; b += 4) s += expsum[(size_t)b * 64 + lane];
        lx[c][lane] = s;
        __syncthreads();
        if (tid < 64) {
            const float tot = lx[0][lane] + lx[1][lane] + lx[2][lane] + lx[3][lane];
            const float avg = tot * (1.f / (float)T_TOKENS);
            float v = avg * avg;
#pragma unroll
            for (int off = 32; off; off >>= 1) v += __shfl_xor(v, off);
            if (lane == 0) out_aux[0] = (float)N_EXP * 0.001f * v;
        }
    }

    const int n = min(*flag_cnt, T_TOKENS);
    for (int i = blockIdx.x; i < n; i += gridDim.x) {
        const int t = flag_list[i];
        __syncthreads();
#pragma unroll
        for (int q = 0; q < 4; ++q) {
            const int o = (q * 256 + tid) * 4;
            *reinterpret_cast<float4*>(&sh[o]) =
                *reinterpret_cast<const float4*>(&h[(size_t)t * D_MODEL + o]);
        }
        __syncthreads();

        const float* wp = &w[(size_t)lane * D_MODEL + c * 1024];
        const float* hp = &sh[c * 1024];
        double acc[8] = {0, 0, 0, 0, 0, 0, 0, 0};
        for (int q = 0; q < 32; ++q) {
            float4 wv8[8], hv8[8];
#pragma unroll
            for (int u = 0; u < 8; ++u) {
                wv8[u] = *reinterpret_cast<const float4*>(&wp[(q * 8 + u) * 4]);
                hv8[u] = *reinterpret_cast<const float4*>(&hp[(q * 8 + u) * 4]);
            }
#pragma unroll
            for (int u = 0; u < 8; ++u) {
                acc[u] = fma((double)hv8[u].x, (double)wv8[u].x, acc[u]);
                acc[u] = fma((double)hv8[u].y, (double)wv8[u].y, acc[u]);
                acc[u] = fma((double)hv8[u].z, (double)wv8[u].z, acc[u]);
                acc[u] = fma((double)hv8[u].w, (double)wv8[u].w, acc[u]);
            }
        }
        sp[c][lane] = (((acc[0] + acc[1]) + (acc[2] + acc[3])) +
                       ((acc[4] + acc[5]) + (acc[6] + acc[7])));
        __syncthreads();

        if (tid < 64) {
            const double mylg = ((sp[0][lane] + sp[1][lane]) +
                                 (sp[2][lane] + sp[3][lane]));
            double m = mylg;
#pragma unroll
            for (int off = 32; off; off >>= 1) m = fmax(m, __shfl_xor(m, off));
            double pv = mylg; int pi = lane;
            double myp = 0.0; int myi = 0; double tsum = 0.0;
#pragma unroll
            for (int r = 0; r < 8; ++r) {
                double bv = pv; int bi = pi;
#pragma unroll
                for (int off = 32; off; off >>= 1) {
                    const double ov = __shfl_xor(bv, off);
                    const int    oi = __shfl_xor(bi, off);
                    if (ov > bv || (ov == bv && oi < bi)) { bv = ov; bi = oi; }
                }
                const double bp = exp(bv - m);
                tsum += bp;
                if (lane == r)  { myp = bp; myi = bi; }
                if (lane == bi) pv = -1.0e300;
            }
            if (lane < 8) {
                out_idx[(size_t)t * 8 + lane] = (float)myi;
                out_w[(size_t)t * 8 + lane]   = (float)(myp / tsum);
            }
        }
    }
}

extern "C" void kernel_launch(void* const* d_in, const int* in_sizes, int n_in,
                              void* d_out, int out_size, void* d_ws, size_t ws_size,
                              hipStream_t stream) {
    const float* h = (const float*)d_in[0];   // [8192,4096]
    const float* w = (const float*)d_in[1];   // [64,4096]
    float* out      = (float*)d_out;
    float* out_idx  = out;                    // 65536 (indices as float)
    float* out_w    = out + 65536;            // 65536
    float* out_aux  = out + 131072;           // 1

    const size_t part_elems = (size_t)T_TOKENS * N_EXP;
    const int NB2 = 512;
    int KS = 8;                               // grid (64,8)=512 blocks = 2/CU
    while (KS > 1 &&
           ((size_t)KS * part_elems * 4 + (size_t)NB2 * 64 * 4 +
            4 + (size_t)T_TOKENS * 4) > ws_size)
        KS >>= 1;

    float* part     = (float*)d_ws;
    float* expsum   = part + (size_t)KS * part_elems;
    int*   flag_cnt = (int*)(expsum + (size_t)NB2 * 64);
    int*   flag_list= flag_cnt + 1;

    dim3 g1(T_TOKENS / 128, KS);
    k_gemm<<<g1, 256, 0, stream>>>(h, w, part, D_MODEL / KS, flag_cnt);
    k_router<<<NB2, 256, 0, stream>>>(part, KS, out_idx, out_w, expsum,
                                      flag_cnt, flag_list);
    k_repair<<<512, 256, 0, stream>>>(h, w, flag_cnt, flag_list, out_idx, out_w,
                                      expsum, NB2, out_aux);
}

// Round 15
// 132.798 us; speedup vs baseline: 1.0316x; 1.0316x over previous
//
#include <hip/hip_runtime.h>

#define T_TOKENS 8192
#define D_MODEL  4096
#define N_EXP    64
#define TAU      1e-6f        // gap threshold for f64 repair (~8 sigma of split-bf16 err)

typedef __attribute__((ext_vector_type(8))) short bf16x8;   // 8 bf16 (4 VGPR)
typedef __attribute__((ext_vector_type(4))) float f32x4;

#define MFMA(A,B,C) __builtin_amdgcn_mfma_f32_16x16x32_bf16(A, B, C, 0, 0, 0)

__device__ __forceinline__ unsigned short bf16rne(float x) {
    unsigned u = __float_as_uint(x);
    return (unsigned short)((u + 0x7FFFu + ((u >> 16) & 1u)) >> 16);
}
__device__ __forceinline__ unsigned pack2(float a, float b, float& ra, float& rb) {
    unsigned short ha = bf16rne(a), hb = bf16rne(b);
    ra = a - __uint_as_float((unsigned)ha << 16);
    rb = b - __uint_as_float((unsigned)hb << 16);
    return (unsigned)ha | ((unsigned)hb << 16);
}
__device__ __forceinline__ void cvt8(const float4& a, const float4& b,
                                     uint4& hi, uint4& lo) {
    float r0,r1,r2,r3,r4,r5,r6,r7;
    hi.x = pack2(a.x, a.y, r0, r1);
    hi.y = pack2(a.z, a.w, r2, r3);
    hi.z = pack2(b.x, b.y, r4, r5);
    hi.w = pack2(b.z, b.w, r6, r7);
    lo.x = (unsigned)bf16rne(r0) | ((unsigned)bf16rne(r1) << 16);
    lo.y = (unsigned)bf16rne(r2) | ((unsigned)bf16rne(r3) << 16);
    lo.z = (unsigned)bf16rne(r4) | ((unsigned)bf16rne(r5) << 16);
    lo.w = (unsigned)bf16rne(r6) | ((unsigned)bf16rne(r7) << 16);
}

// ---------------------------------------------------------------------------
// Kernel 1: split-bf16 MFMA partial GEMM (hh*wh + hh*wl + hl*wh; err sigma
// ~1.2e-7 << TAU window -> flag+repair keeps exact top-k). R13's exact
// depth-1 structure (best measured; R14's depth-2 regressed via VGPR
// pressure). Block (0,0) zeroes flag_cnt (replaces memset node, -6.6us).
// ---------------------------------------------------------------------------
__global__ __launch_bounds__(256) void k_gemm(const float* __restrict__ h,
                                              const float* __restrict__ w,
                                              float* __restrict__ part,
                                              int ks_len,
                                              int* __restrict__ flag_cnt) {
    __shared__ unsigned short LHS[2][2][128][40]; // [dbuf][hi/lo][tok][kpad] 40 KB
    __shared__ unsigned short LWS[2][2][64][40];  // 20 KB  => 60 KB total
    const int tid  = threadIdx.x;
    const int wv   = tid >> 6;
    const int lane = tid & 63;
    const int T0   = blockIdx.x * 128;
    const int k0   = blockIdx.y * ks_len;
    const int wr   = wv & 1;        // token half (64 tokens)
    const int wc   = wv >> 1;       // expert half (32 experts)
    const int lq   = lane >> 4;     // quarter 0..3
    const int lr   = lane & 15;
    const int koff = lq * 8;        // frag k-offset (bf16 elems)

    if (blockIdx.x == 0 && blockIdx.y == 0 && tid == 0) *flag_cnt = 0;

    const int hrow = tid & 127, hq = (tid >> 7) * 16;
    const int wrow = tid & 63,  wq = (tid >> 6) * 8;
    const float* gh = h + (size_t)(T0 + hrow) * D_MODEL + k0 + hq;
    const float* gw = w + (size_t)wrow * D_MODEL + k0 + wq;

    f32x4 acc[4][2];
#pragma unroll
    for (int i = 0; i < 4; ++i)
#pragma unroll
        for (int j = 0; j < 2; ++j)
#pragma unroll
            for (int x = 0; x < 4; ++x) acc[i][j][x] = 0.f;

    float4 h0, h1, h2, h3, w0, w1;      // prefetch regs (static names)
    auto gload = [&](int it) {
        const float* p = gh + it * 32;
        h0 = *(const float4*)(p);      h1 = *(const float4*)(p + 4);
        h2 = *(const float4*)(p + 8);  h3 = *(const float4*)(p + 12);
        const float* q = gw + it * 32;
        w0 = *(const float4*)(q);      w1 = *(const float4*)(q + 4);
    };
    auto writebuf = [&](int nb) {
        uint4 hi, lo;
        cvt8(h0, h1, hi, lo);
        *(uint4*)&LHS[nb][0][hrow][hq]     = hi;
        *(uint4*)&LHS[nb][1][hrow][hq]     = lo;
        cvt8(h2, h3, hi, lo);
        *(uint4*)&LHS[nb][0][hrow][hq + 8] = hi;
        *(uint4*)&LHS[nb][1][hrow][hq + 8] = lo;
        cvt8(w0, w1, hi, lo);
        *(uint4*)&LWS[nb][0][wrow][wq]     = hi;
        *(uint4*)&LWS[nb][1][wrow][wq]     = lo;
    };

    const int nt = ks_len >> 5;         // 16 tiles at KS=8
    gload(0);
    writebuf(0);
    __syncthreads();
    for (int it = 0; it < nt; ++it) {
        const int b = it & 1;
        if (it + 1 < nt) gload(it + 1);             // lands during MFMA phase
        const bf16x8 Bh0 = *(const bf16x8*)&LWS[b][0][wc * 32 + lr][koff];
        const bf16x8 Bl0 = *(const bf16x8*)&LWS[b][1][wc * 32 + lr][koff];
        const bf16x8 Bh1 = *(const bf16x8*)&LWS[b][0][wc * 32 + 16 + lr][koff];
        const bf16x8 Bl1 = *(const bf16x8*)&LWS[b][1][wc * 32 + 16 + lr][koff];
#pragma unroll
        for (int i4 = 0; i4 < 4; ++i4) {
            const bf16x8 Ah = *(const bf16x8*)&LHS[b][0][wr * 64 + i4 * 16 + lr][koff];
            const bf16x8 Al = *(const bf16x8*)&LHS[b][1][wr * 64 + i4 * 16 + lr][koff];
            acc[i4][0] = MFMA(Ah, Bh0, acc[i4][0]);
            acc[i4][1] = MFMA(Ah, Bh1, acc[i4][1]);
            acc[i4][0] = MFMA(Ah, Bl0, acc[i4][0]);
            acc[i4][1] = MFMA(Ah, Bl1, acc[i4][1]);
            acc[i4][0] = MFMA(Al, Bh0, acc[i4][0]);
            acc[i4][1] = MFMA(Al, Bh1, acc[i4][1]);
        }
        if (it + 1 < nt) writebuf(b ^ 1);           // vmcnt wait lands here
        __syncthreads();
    }

    // C/D layout (m89-verified): col = lane&15, row = (lane>>4)*4 + reg
    float* pb = part + (size_t)blockIdx.y * T_TOKENS * N_EXP;
#pragma unroll
    for (int i4 = 0; i4 < 4; ++i4)
#pragma unroll
        for (int j = 0; j < 2; ++j)
#pragma unroll
            for (int i = 0; i < 4; ++i) {
                const int t = T0 + wr * 64 + i4 * 16 + lq * 4 + i;
                const int e = wc * 32 + j * 16 + lr;
                pb[(size_t)t * N_EXP + e] = acc[i4][j][i];
            }
}

// ---------------------------------------------------------------------------
// Kernel 2: per-token softmax + top-8 + gap-based tie flagging + aux partials.
// block 256 (4 waves), wave handles 4 tokens, lane = expert. f32 throughout.
// ---------------------------------------------------------------------------
__global__ __launch_bounds__(256) void k_router(const float* __restrict__ part, int KS,
                                                float* __restrict__ out_idx,
                                                float* __restrict__ out_w,
                                                float* __restrict__ expsum,
                                                int* __restrict__ flag_cnt,
                                                int* __restrict__ flag_list) {
    __shared__ float laux[4][64];
    const int lane = threadIdx.x & 63;
    const int wid  = threadIdx.x >> 6;
    float aux_acc = 0.f;
    const int tbase = blockIdx.x * 16 + wid * 4;
    const size_t kstride = (size_t)T_TOKENS * N_EXP;

    for (int tt = 0; tt < 4; ++tt) {
        const int t = tbase + tt;
        const float* pb = part + (size_t)t * N_EXP + lane;
        float a0 = 0.f, a1 = 0.f, a2 = 0.f, a3 = 0.f;
        int ksi = 0;
        for (; ksi + 4 <= KS; ksi += 4) {
            a0 += pb[(size_t)(ksi + 0) * kstride];
            a1 += pb[(size_t)(ksi + 1) * kstride];
            a2 += pb[(size_t)(ksi + 2) * kstride];
            a3 += pb[(size_t)(ksi + 3) * kstride];
        }
        for (; ksi < KS; ++ksi) a0 += pb[(size_t)ksi * kstride];
        const float lg = (a0 + a1) + (a2 + a3);

        float m = lg;
#pragma unroll
        for (int off = 32; off; off >>= 1) m = fmaxf(m, __shfl_xor(m, off));
        const float p = __expf(lg - m);
        float s = p;
#pragma unroll
        for (int off = 32; off; off >>= 1) s += __shfl_xor(s, off);
        const float inv_s = 1.f / s;
        aux_acc += p * inv_s;

        float pv = lg; int pi = lane;
        float myp = 0.f; int myi = 0; float tsum = 0.f, prev = 0.f;
        bool flg = false;
#pragma unroll
        for (int r = 0; r < 9; ++r) {
            float bv = pv; int bi = pi;
#pragma unroll
            for (int off = 32; off; off >>= 1) {
                const float ov = __shfl_xor(bv, off);
                const int   oi = __shfl_xor(bi, off);
                if (ov > bv || (ov == bv && oi < bi)) { bv = ov; bi = oi; }
            }
            if (r > 0) flg = flg || (prev - bv < TAU);
            prev = bv;
            if (r < 8) {
                const float bp = __expf(bv - m) * inv_s;
                tsum += bp;
                if (lane == r)  { myp = bp; myi = bi; }
                if (lane == bi) pv = -1e30f;
            }
        }
        if (lane < 8) {
            out_idx[(size_t)t * 8 + lane] = (float)myi;
            out_w[(size_t)t * 8 + lane]   = myp / tsum;
        }
        if (lane == 0 && flg) {
            const int pos = atomicAdd(flag_cnt, 1);
            if (pos < T_TOKENS) flag_list[pos] = t;
        }
    }

    laux[wid][lane] = aux_acc;
    __syncthreads();
    if (threadIdx.x < 64)
        expsum[(size_t)blockIdx.x * 64 + threadIdx.x] =
            laux[0][threadIdx.x] + laux[1][threadIdx.x] +
            laux[2][threadIdx.x] + laux[3][threadIdx.x];
}

// ---------------------------------------------------------------------------
// Kernel 3: f64 repair (one block per flagged token) + FUSED aux finalize.
// ---------------------------------------------------------------------------
__global__ __launch_bounds__(256) void k_repair(const float* __restrict__ h,
                                                const float* __restrict__ w,
                                                const int* __restrict__ flag_cnt,
                                                const int* __restrict__ flag_list,
                                                float* __restrict__ out_idx,
                                                float* __restrict__ out_w,
                                                const float* __restrict__ expsum,
                                                int nb,
                                                float* __restrict__ out_aux) {
    __shared__ float  sh[D_MODEL];   // 16 KB
    __shared__ double sp[4][64];     //  2 KB
    __shared__ float  lx[4][64];     //  1 KB (aux)
    const int tid  = threadIdx.x;
    const int lane = tid & 63;
    const int c    = tid >> 6;

    if (blockIdx.x == 0) {           // fused aux finalize
        float s = 0.f;
        for (int b = c; b < nb; b += 4) s += expsum[(size_t)b * 64 + lane];
        lx[c][lane] = s;
        __syncthreads();
        if (tid < 64) {
            const float tot = lx[0][lane] + lx[1][lane] + lx[2][lane] + lx[3][lane];
            const float avg = tot * (1.f / (float)T_TOKENS);
            float v = avg * avg;
#pragma unroll
            for (int off = 32; off; off >>= 1) v += __shfl_xor(v, off);
            if (lane == 0) out_aux[0] = (float)N_EXP * 0.001f * v;
        }
    }

    const int n = min(*flag_cnt, T_TOKENS);
    for (int i = blockIdx.x; i < n; i += gridDim.x) {
        const int t = flag_list[i];
        __syncthreads();
#pragma unroll
        for (int q = 0; q < 4; ++q) {
            const int o = (q * 256 + tid) * 4;
            *reinterpret_cast<float4*>(&sh[o]) =
                *reinterpret_cast<const float4*>(&h[(size_t)t * D_MODEL + o]);
        }
        __syncthreads();

        const float* wp = &w[(size_t)lane * D_MODEL + c * 1024];
        const float* hp = &sh[c * 1024];
        double acc[8] = {0, 0, 0, 0, 0, 0, 0, 0};
        for (int q = 0; q < 32; ++q) {
            float4 wv8[8], hv8[8];
#pragma unroll
            for (int u = 0; u < 8; ++u) {
                wv8[u] = *reinterpret_cast<const float4*>(&wp[(q * 8 + u) * 4]);
                hv8[u] = *reinterpret_cast<const float4*>(&hp[(q * 8 + u) * 4]);
            }
#pragma unroll
            for (int u = 0; u < 8; ++u) {
                acc[u] = fma((double)hv8[u].x, (double)wv8[u].x, acc[u]);
                acc[u] = fma((double)hv8[u].y, (double)wv8[u].y, acc[u]);
                acc[u] = fma((double)hv8[u].z, (double)wv8[u].z, acc[u]);
                acc[u] = fma((double)hv8[u].w, (double)wv8[u].w, acc[u]);
            }
        }
        sp[c][lane] = (((acc[0] + acc[1]) + (acc[2] + acc[3])) +
                       ((acc[4] + acc[5]) + (acc[6] + acc[7])));
        __syncthreads();

        if (tid < 64) {
            const double mylg = ((sp[0][lane] + sp[1][lane]) +
                                 (sp[2][lane] + sp[3][lane]));
            double m = mylg;
#pragma unroll
            for (int off = 32; off; off >>= 1) m = fmax(m, __shfl_xor(m, off));
            double pv = mylg; int pi = lane;
            double myp = 0.0; int myi = 0; double tsum = 0.0;
#pragma unroll
            for (int r = 0; r < 8; ++r) {
                double bv = pv; int bi = pi;
#pragma unroll
                for (int off = 32; off; off >>= 1) {
                    const double ov = __shfl_xor(bv, off);
                    const int    oi = __shfl_xor(bi, off);
                    if (ov > bv || (ov == bv && oi < bi)) { bv = ov; bi = oi; }
                }
                const double bp = exp(bv - m);
                tsum += bp;
                if (lane == r)  { myp = bp; myi = bi; }
                if (lane == bi) pv = -1.0e300;
            }
            if (lane < 8) {
                out_idx[(size_t)t * 8 + lane] = (float)myi;
                out_w[(size_t)t * 8 + lane]   = (float)(myp / tsum);
            }
        }
    }
}

extern "C" void kernel_launch(void* const* d_in, const int* in_sizes, int n_in,
                              void* d_out, int out_size, void* d_ws, size_t ws_size,
                              hipStream_t stream) {
    const float* h = (const float*)d_in[0];   // [8192,4096]
    const float* w = (const float*)d_in[1];   // [64,4096]
    float* out      = (float*)d_out;
    float* out_idx  = out;                    // 65536 (indices as float)
    float* out_w    = out + 65536;            // 65536
    float* out_aux  = out + 131072;           // 1

    const size_t part_elems = (size_t)T_TOKENS * N_EXP;
    const int NB2 = 512;
    int KS = 8;                               // grid (64,8)=512 blocks = 2/CU
    while (KS > 1 &&
           ((size_t)KS * part_elems * 4 + (size_t)NB2 * 64 * 4 +
            4 + (size_t)T_TOKENS * 4) > ws_size)
        KS >>= 1;

    float* part     = (float*)d_ws;
    float* expsum   = part + (size_t)KS * part_elems;
    int*   flag_cnt = (int*)(expsum + (size_t)NB2 * 64);
    int*   flag_list= flag_cnt + 1;

    dim3 g1(T_TOKENS / 128, KS);
    k_gemm<<<g1, 256, 0, stream>>>(h, w, part, D_MODEL / KS, flag_cnt);
    k_router<<<NB2, 256, 0, stream>>>(part, KS, out_idx, out_w, expsum,
                                      flag_cnt, flag_list);
    k_repair<<<512, 256, 0, stream>>>(h, w, flag_cnt, flag_list, out_idx, out_w,
                                      expsum, NB2, out_aux);
}